// Round 4
// baseline (161.357 us; speedup 1.0000x reference)
//
#include <hip/hip_runtime.h>
#include <hip/hip_bf16.h>

#define NN 8192
#define IND 512
#define OUTD 64
#define ALPHA_ 0.2f
#define LOG2E 1.4426950408889634f

typedef float f32x4 __attribute__((ext_vector_type(4)));
typedef short s16x8 __attribute__((ext_vector_type(8)));
typedef int   i32x4 __attribute__((ext_vector_type(4)));
typedef unsigned int uint;

static __device__ __forceinline__ short f2bf(float x) {
    __hip_bfloat16 b = __float2bfloat16(x);
    return *reinterpret_cast<short*>(&b);
}
// monotone float<->uint encode for atomicMax over floats
static __device__ __forceinline__ uint fenc(float f) {
    uint u = __float_as_uint(f);
    return (u & 0x80000000u) ? ~u : (u | 0x80000000u);
}
static __device__ __forceinline__ float fdec(uint k) {
    uint u = (k & 0x80000000u) ? (k & 0x7FFFFFFFu) : ~k;
    return __uint_as_float(u);
}

#define GLD_LDS16(g, d) \
    __builtin_amdgcn_global_load_lds((const __attribute__((address_space(1))) int*)(g), \
                                     (__attribute__((address_space(3))) int*)(d), 16, 0, 0)

// ---- kernel 1: Wh = h@W; whT bf16 [64][8192]; Wh1s/Wh2s prescaled by log2e; atomic max of Wh2s ----
__global__ __launch_bounds__(256) void k_wh(const float* __restrict__ h,
                                            const float* __restrict__ W,
                                            const float* __restrict__ a,
                                            __hip_bfloat16* __restrict__ whT,
                                            float* __restrict__ Wh1s,
                                            float* __restrict__ Wh2s,
                                            uint* __restrict__ mxk) {
    __shared__ float hs[8 * IND];      // 16 KB
    int tid = threadIdx.x;
    const f32x4* h4 = (const f32x4*)(h + (size_t)blockIdx.x * 8 * IND);
    f32x4* hs4 = (f32x4*)hs;
    #pragma unroll
    for (int t = 0; t < 4; ++t) hs4[tid + t * 256] = h4[tid + t * 256];
    __syncthreads();

    int w = tid >> 6, l = tid & 63;
    int g = l >> 4, lc = l & 15;
    int c4 = lc * 4;
    const float* hrow = hs + (w * 2) * IND;
    f32x4 acc0 = {0.f, 0.f, 0.f, 0.f};
    f32x4 acc1 = {0.f, 0.f, 0.f, 0.f};

    #pragma unroll 4
    for (int k0 = 0; k0 < 128; ++k0) {
        int k = k0 * 4 + g;
        f32x4 wv = *(const f32x4*)(W + k * OUTD + c4);
        float h0 = hrow[k];
        float h1 = hrow[IND + k];
        acc0[0] = fmaf(h0, wv[0], acc0[0]);
        acc0[1] = fmaf(h0, wv[1], acc0[1]);
        acc0[2] = fmaf(h0, wv[2], acc0[2]);
        acc0[3] = fmaf(h0, wv[3], acc0[3]);
        acc1[0] = fmaf(h1, wv[0], acc1[0]);
        acc1[1] = fmaf(h1, wv[1], acc1[1]);
        acc1[2] = fmaf(h1, wv[2], acc1[2]);
        acc1[3] = fmaf(h1, wv[3], acc1[3]);
    }

    #pragma unroll
    for (int e = 0; e < 4; ++e) {
        acc0[e] += __shfl_xor(acc0[e], 16, 64);
        acc0[e] += __shfl_xor(acc0[e], 32, 64);
        acc1[e] += __shfl_xor(acc1[e], 16, 64);
        acc1[e] += __shfl_xor(acc1[e], 32, 64);
    }

    int row0 = blockIdx.x * 8 + w * 2;
    if (g == 0) {
        #pragma unroll
        for (int e = 0; e < 4; ++e) {
            whT[(size_t)(c4 + e) * NN + row0]     = __float2bfloat16(acc0[e]);
            whT[(size_t)(c4 + e) * NN + row0 + 1] = __float2bfloat16(acc1[e]);
        }
    }

    float p10 = 0.f, p20 = 0.f, p11 = 0.f, p21 = 0.f;
    #pragma unroll
    for (int e = 0; e < 4; ++e) {
        float a1 = a[c4 + e], a2 = a[OUTD + c4 + e];
        p10 = fmaf(acc0[e], a1, p10);
        p20 = fmaf(acc0[e], a2, p20);
        p11 = fmaf(acc1[e], a1, p11);
        p21 = fmaf(acc1[e], a2, p21);
    }
    #pragma unroll
    for (int off = 1; off < 16; off <<= 1) {
        p10 += __shfl_xor(p10, off, 64);
        p20 += __shfl_xor(p20, off, 64);
        p11 += __shfl_xor(p11, off, 64);
        p21 += __shfl_xor(p21, off, 64);
    }
    if (l == 0) {
        float s20 = p20 * LOG2E, s21 = p21 * LOG2E;
        Wh1s[row0]     = p10 * LOG2E;  Wh2s[row0]     = s20;
        Wh1s[row0 + 1] = p11 * LOG2E;  Wh2s[row0 + 1] = s21;
        atomicMax(mxk, fenc(fmaxf(s20, s21)));
    }
}

// ---- kernel 2: fused mask+softmax+PV with LDS-staged adj (rotated layout, gload_lds) ----
__global__ __launch_bounds__(512) void k_gat(const int* __restrict__ adj,
                                             const __hip_bfloat16* __restrict__ whT,
                                             const float* __restrict__ Wh1s,
                                             const float* __restrict__ Wh2s,
                                             const uint* __restrict__ mxk,
                                             float* __restrict__ out) {
    __shared__ char smem[49152];                       // 3x16KB adj staging, reused as epilogue lacc
    int (*sbuf)[16][256] = (int(*)[16][256])smem;      // [3][16][256] ints
    float (*lacc)[16][65] = (float(*)[16][65])smem;    // [8][16][65]
    float (*lls)[16] = (float(*)[16])(smem + 8 * 16 * 65 * 4);

    int tid = threadIdx.x;
    int w   = tid >> 6;        // wave 0..7
    int l   = tid & 63;
    int lr  = l & 15;          // A-row / B-col within 16-tile
    int grp = l >> 4;          // k-group (8 consecutive j per lane)
    int ib  = blockIdx.x * 16;
    int row = ib + lr;

    float wh1s = Wh1s[row];
    float t0 = wh1s + fdec(*mxk);          // upper bound (scaled domain; leakyrelu monotone, scale>0)
    float mcs = fmaxf(t0, ALPHA_ * t0);

    f32x4 acc0 = {0.f, 0.f, 0.f, 0.f};
    f32x4 acc1 = acc0, acc2 = acc0, acc3 = acc0, acc4 = acc0;
    s16x8 bones;
    #pragma unroll
    for (int e = 0; e < 8; ++e) bones[e] = (short)0x3F80;   // bf16 1.0

    // staging: wave w owns tile rows 2w, 2w+1. Rotated source so LDS stays linear:
    // LDS word (r, pw) holds logical word (pw - 8r) & 255 of the 256-int chunk.
    int r0 = 2 * w, r1 = 2 * w + 1;
    const int* g0 = adj + (size_t)(ib + r0) * NN + ((l * 4 - 8 * r0) & 255);
    const int* g1 = adj + (size_t)(ib + r1) * NN + ((l * 4 - 8 * r1) & 255);

    // read-back: logical words w0..w0+7 of row lr -> phys (w0+8*lr)&255 ...
    int w0 = w * 32 + grp * 8;
    int p0 = (w0 + 8 * lr) & 255;
    int p1 = (w0 + 4 + 8 * lr) & 255;

    const __hip_bfloat16* bp = whT + (size_t)lr * NN;

#define STAGE(b, itc) do {                                   \
        GLD_LDS16(g0 + (size_t)(itc) * 256, &sbuf[b][r0][0]); \
        GLD_LDS16(g1 + (size_t)(itc) * 256, &sbuf[b][r1][0]); \
    } while (0)

    STAGE(0, 0);
    STAGE(1, 1);

    for (int it = 0; it < 32; ++it) {
        __syncthreads();                   // drains this wave's outstanding stages (vmcnt) + syncs block
        if (it < 30) STAGE((it + 2) % 3, it + 2);

        const int* rb = &sbuf[it % 3][lr][0];
        i32x4 a0 = *(const i32x4*)(rb + p0);
        i32x4 a1 = *(const i32x4*)(rb + p1);

        int jl = it * 256 + w0;
        f32x4 w20 = *(const f32x4*)(Wh2s + jl);
        f32x4 w21 = *(const f32x4*)(Wh2s + jl + 4);
        s16x8 b0 = *(const s16x8*)(bp + jl);
        s16x8 b1 = *(const s16x8*)(bp + (size_t)16 * NN + jl);
        s16x8 b2 = *(const s16x8*)(bp + (size_t)32 * NN + jl);
        s16x8 b3 = *(const s16x8*)(bp + (size_t)48 * NN + jl);

        s16x8 af;
        #pragma unroll
        for (int e = 0; e < 4; ++e) {
            float t = wh1s + w20[e];
            float x = fmaxf(t, ALPHA_ * t);            // leaky relu (scaled domain)
            float p = exp2f(x - mcs);
            p = (a0[e] != 0) ? p : 0.f;
            af[e] = f2bf(p);
        }
        #pragma unroll
        for (int e = 0; e < 4; ++e) {
            float t = wh1s + w21[e];
            float x = fmaxf(t, ALPHA_ * t);
            float p = exp2f(x - mcs);
            p = (a1[e] != 0) ? p : 0.f;
            af[e + 4] = f2bf(p);
        }
        acc0 = __builtin_amdgcn_mfma_f32_16x16x32_bf16(af, b0, acc0, 0, 0, 0);
        acc1 = __builtin_amdgcn_mfma_f32_16x16x32_bf16(af, b1, acc1, 0, 0, 0);
        acc2 = __builtin_amdgcn_mfma_f32_16x16x32_bf16(af, b2, acc2, 0, 0, 0);
        acc3 = __builtin_amdgcn_mfma_f32_16x16x32_bf16(af, b3, acc3, 0, 0, 0);
        acc4 = __builtin_amdgcn_mfma_f32_16x16x32_bf16(af, bones, acc4, 0, 0, 0); // row-sum = softmax denom
    }
#undef STAGE

    __syncthreads();                       // done with sbuf; reuse as lacc

    #pragma unroll
    for (int reg = 0; reg < 4; ++reg) {
        int rr = grp * 4 + reg;            // C layout: row=(lane>>4)*4+reg, col=lane&15
        lacc[w][rr][lr]      = acc0[reg];
        lacc[w][rr][16 + lr] = acc1[reg];
        lacc[w][rr][32 + lr] = acc2[reg];
        lacc[w][rr][48 + lr] = acc3[reg];
    }
    if (lr == 0) {
        #pragma unroll
        for (int reg = 0; reg < 4; ++reg) lls[w][grp * 4 + reg] = acc4[reg];
    }
    __syncthreads();

    #pragma unroll
    for (int t = 0; t < 2; ++t) {
        int idx = tid + t * 512;           // 1024 outputs: 16 rows x 64 cols
        int rr = idx >> 6, c = idx & 63;
        float v = 0.f, ls = 0.f;
        #pragma unroll
        for (int ww = 0; ww < 8; ++ww) {
            v += lacc[ww][rr][c];
            ls += lls[ww][rr];
        }
        float hv = v / ls;
        out[(size_t)(ib + rr) * OUTD + c] = hv > 0.f ? hv : exp2f(hv * LOG2E) - 1.f;
    }
}

extern "C" void kernel_launch(void* const* d_in, const int* in_sizes, int n_in,
                              void* d_out, int out_size, void* d_ws, size_t ws_size,
                              hipStream_t stream) {
    const float* h   = (const float*)d_in[0];
    const int*   adj = (const int*)d_in[1];
    const float* W   = (const float*)d_in[2];
    const float* a   = (const float*)d_in[3];
    float* out = (float*)d_out;

    char* ws = (char*)d_ws;
    __hip_bfloat16*  whT  = (__hip_bfloat16*)ws;                     // 1 MB
    float*           Wh1s = (float*)(ws + 1048576);                  // 32 KB
    float*           Wh2s = Wh1s + NN;                               // 32 KB
    uint*            mxk  = (uint*)(Wh2s + NN);                      // 4 B

    hipMemsetAsync(mxk, 0, 4, stream);     // encoded -inf identity
    k_wh<<<NN / 8, 256, 0, stream>>>(h, W, a, whT, Wh1s, Wh2s, mxk);
    k_gat<<<NN / 16, 512, 0, stream>>>(adj, whT, Wh1s, Wh2s, mxk, out);
}